// Round 12
// baseline (47.769 us; speedup 1.0000x reference)
//
#include <hip/hip_runtime.h>
#include <cmath>

// Problem constants: B=4, T=1, DIN=4096, DOUT=11008, RANK=512
constexpr int DIN  = 4096;
constexpr int DOUT = 11008;
constexpr int RANK = 512;
constexpr int NB   = 4;

constexpr int NCHUNK = 256;          // d-chunks for lr partials
constexpr int DCH    = DIN / NCHUNK; // 16 d's per chunk

constexpr int ROWS   = 4;            // rows per block (2 waves x 2 rows)
constexpr int CHUNK  = 256;          // floats per chunk per row (1 gload_lds16/row)
constexpr int CH4    = CHUNK / 4;    // 64 float4
constexpr int NCH    = DIN / CHUNK;  // 16 chunks (full K)
constexpr int NBUF   = 3;            // LDS pipeline depth (2-ahead prefetch)

#define GLOAD_LDS16(gsrc, ldst)                                                   \
    __builtin_amdgcn_global_load_lds(                                             \
        (const __attribute__((address_space(1))) void*)(gsrc),                    \
        (__attribute__((address_space(3))) void*)(ldst), 16, 0, 0)

#define WAITV(n) asm volatile("s_waitcnt vmcnt(" #n ")" ::: "memory")

// ---------------------------------------------------------------------------
// Phase 1 (fused prep): xs[b][d] = x*mask -> ws;  xc = x*(1-mask) -> LDS;
// partial[chunk][b][r] = sum_{d in chunk} xc[b][d] * V[d][r]
// ---------------------------------------------------------------------------
__global__ __launch_bounds__(512)
void lr_partial_kernel(const float* __restrict__ x,
                       const float* __restrict__ scale,
                       const float* __restrict__ thp,
                       const float* __restrict__ V,
                       float* __restrict__ partial,
                       float* __restrict__ xs)
{
    __shared__ float xc[NB * DCH];
    const int chunk = blockIdx.x;
    const int t = threadIdx.x;
    const float th = thp[0];
    if (t < NB * DCH) {
        const int b = t / DCH, dd = t % DCH;
        const int d = chunk * DCH + dd;
        const float xv = x[b * DIN + d];
        const bool keep = fabsf(xv * scale[d]) > th; // mask==1 -> sparse path
        xc[t] = keep ? 0.f : xv;
        xs[b * DIN + d] = keep ? xv : 0.f;
    }
    __syncthreads();
    const int r = t; // 0..511
    float a0 = 0.f, a1 = 0.f, a2 = 0.f, a3 = 0.f;
    #pragma unroll
    for (int dd = 0; dd < DCH; ++dd) {
        const float v = V[(size_t)(chunk * DCH + dd) * RANK + r];
        a0 = fmaf(xc[0 * DCH + dd], v, a0);
        a1 = fmaf(xc[1 * DCH + dd], v, a1);
        a2 = fmaf(xc[2 * DCH + dd], v, a2);
        a3 = fmaf(xc[3 * DCH + dd], v, a3);
    }
    float* p = partial + (size_t)chunk * (NB * RANK) + r;
    p[0 * RANK] = a0;
    p[1 * RANK] = a1;
    p[2 * RANK] = a2;
    p[3 * RANK] = a3;
}

// ---------------------------------------------------------------------------
// Phase 2: lr[b][r] = S[r] * sum_chunk partial[chunk][b][r]
// ---------------------------------------------------------------------------
__global__ __launch_bounds__(256)
void lr_reduce_kernel(const float* __restrict__ partial,
                      const float* __restrict__ S,
                      float* __restrict__ lr)
{
    const int t = blockIdx.x * 256 + threadIdx.x;
    const int idx = t >> 4;  // output index 0..NB*RANK-1
    const int s = t & 15;    // chunk-subset
    float sum = 0.f;
    #pragma unroll
    for (int j = 0; j < 16; ++j)
        sum += partial[(size_t)(s * 16 + j) * (NB * RANK) + idx];
    #pragma unroll
    for (int m = 8; m >= 1; m >>= 1)
        sum += __shfl_xor(sum, m, 64);
    if (s == 0)
        lr[idx] = sum * S[idx & (RANK - 1)];
}

// ---------------------------------------------------------------------------
// Main (full-K, direct output): out[b][o] = bias[o] + sum_d xs[b][d]*W[o][d]
//                                           + sum_r lr[b][r]*U[o][r]
// Barrier-free global_load_lds pipeline, counted vmcnt, NBUF=3, 2-ahead.
// ROWS=4 / 128-thread blocks: grid 2752 -> ~10.75 blocks/CU, 13/CU capacity
// (12 KB LDS) -> all co-resident, per-CU work imbalance ~2% (was ~12%).
// ---------------------------------------------------------------------------
__global__ __launch_bounds__(128)
void rsparse_main_kernel(const float* __restrict__ xs,
                         const float* __restrict__ W,
                         const float* __restrict__ U,
                         const float* __restrict__ lr,
                         const float* __restrict__ bias,
                         float* __restrict__ out)
{
    __shared__ float sbuf[NBUF * ROWS * CHUNK]; // 12 KB
    const int tid  = threadIdx.x;
    const int wave = tid >> 6, lane = tid & 63;
    const int o0   = blockIdx.x * ROWS;
    const int r0   = wave * 2, r1 = r0 + 1;  // this wave's rows

    const float4* __restrict__ XS = (const float4*)xs; // [NB][1024]

    const float* Wr0 = W + (size_t)(o0 + r0) * DIN + lane * 4;
    const float* Wr1 = W + (size_t)(o0 + r1) * DIN + lane * 4;

    // stage chunk c into buffer slot `buf` (this wave's 2 rows only)
    auto STAGE = [&](int buf, int c) {
        GLOAD_LDS16(Wr0 + c * CHUNK, &sbuf[buf * (ROWS * CHUNK) + r0 * CHUNK]);
        GLOAD_LDS16(Wr1 + c * CHUNK, &sbuf[buf * (ROWS * CHUNK) + r1 * CHUNK]);
    };

    float acc0[NB] = {0.f, 0.f, 0.f, 0.f};
    float acc1[NB] = {0.f, 0.f, 0.f, 0.f};

    STAGE(0, 0);
    STAGE(1, 1);

    #pragma unroll
    for (int c = 0; c < NCH; ++c) {
        if (c + 2 < NCH)
            STAGE((c + 2) % NBUF, c + 2);

        // wait until chunk c's 2 loads landed; keep newer chunks in flight
        if (c < NCH - 2)       WAITV(4);
        else if (c == NCH - 2) WAITV(2);
        else                   WAITV(0);
        __builtin_amdgcn_sched_barrier(0); // no hoisting across the wait

        const float4* wb = (const float4*)&sbuf[(c % NBUF) * (ROWS * CHUNK)];
        const float4 w0 = wb[r0 * CH4 + lane];
        const float4 w1 = wb[r1 * CH4 + lane];
        const int x4 = c * CH4 + lane;
        #pragma unroll
        for (int b = 0; b < NB; ++b) {
            const float4 xv = XS[b * 1024 + x4];
            acc0[b] = fmaf(w0.x, xv.x, acc0[b]);
            acc0[b] = fmaf(w0.y, xv.y, acc0[b]);
            acc0[b] = fmaf(w0.z, xv.z, acc0[b]);
            acc0[b] = fmaf(w0.w, xv.w, acc0[b]);
            acc1[b] = fmaf(w1.x, xv.x, acc1[b]);
            acc1[b] = fmaf(w1.y, xv.y, acc1[b]);
            acc1[b] = fmaf(w1.z, xv.z, acc1[b]);
            acc1[b] = fmaf(w1.w, xv.w, acc1[b]);
        }
    }

    { // U.lr compensation for this wave's 2 rows
        const float4* __restrict__ U0 = (const float4*)(U + (size_t)(o0 + r0) * RANK);
        const float4* __restrict__ U1 = (const float4*)(U + (size_t)(o0 + r1) * RANK);
        const float4* __restrict__ LR = (const float4*)lr; // [NB][128]
        #pragma unroll
        for (int j = 0; j < 2; ++j) {
            const int c = (j << 6) + lane; // 0..127
            const float4 u0 = U0[c];
            const float4 u1 = U1[c];
            #pragma unroll
            for (int b = 0; b < NB; ++b) {
                const float4 lv = LR[b * 128 + c];
                acc0[b] = fmaf(u0.x, lv.x, acc0[b]);
                acc0[b] = fmaf(u0.y, lv.y, acc0[b]);
                acc0[b] = fmaf(u0.z, lv.z, acc0[b]);
                acc0[b] = fmaf(u0.w, lv.w, acc0[b]);
                acc1[b] = fmaf(u1.x, lv.x, acc1[b]);
                acc1[b] = fmaf(u1.y, lv.y, acc1[b]);
                acc1[b] = fmaf(u1.z, lv.z, acc1[b]);
                acc1[b] = fmaf(u1.w, lv.w, acc1[b]);
            }
        }
    }

    // 64-lane butterfly reduction
    #pragma unroll
    for (int b = 0; b < NB; ++b) {
        #pragma unroll
        for (int m = 32; m >= 1; m >>= 1) {
            acc0[b] += __shfl_xor(acc0[b], m, 64);
            acc1[b] += __shfl_xor(acc1[b], m, 64);
        }
    }

    if (lane == 0) {
        const float bi0 = bias[o0 + r0], bi1 = bias[o0 + r1];
        #pragma unroll
        for (int b = 0; b < NB; ++b) {
            out[b * DOUT + o0 + r0] = acc0[b] + bi0;
            out[b * DOUT + o0 + r1] = acc1[b] + bi1;
        }
    }
}

// ---------------------------------------------------------------------------
extern "C" void kernel_launch(void* const* d_in, const int* in_sizes, int n_in,
                              void* d_out, int out_size, void* d_ws, size_t ws_size,
                              hipStream_t stream)
{
    const float* x     = (const float*)d_in[0]; // [4][1][4096]
    const float* W     = (const float*)d_in[1]; // [11008][4096]
    const float* bias  = (const float*)d_in[2]; // [11008]
    const float* U     = (const float*)d_in[3]; // [11008][512]
    const float* S     = (const float*)d_in[4]; // [512]
    const float* V     = (const float*)d_in[5]; // [4096][512]
    const float* scale = (const float*)d_in[6]; // [4096]
    const float* thp   = (const float*)d_in[7]; // [1]
    float* out = (float*)d_out;                 // [4][1][11008]

    float* partial = (float*)d_ws;                          // 2 MB
    float* lr      = partial + (size_t)NCHUNK * NB * RANK;  // 8 KB
    float* xs      = lr + NB * RANK;                        // 64 KB

    lr_partial_kernel<<<NCHUNK, 512, 0, stream>>>(x, scale, thp, V, partial, xs);
    lr_reduce_kernel<<<(NB * RANK * 16) / 256, 256, 0, stream>>>(partial, S, lr);
    rsparse_main_kernel<<<DOUT / ROWS, 128, 0, stream>>>(xs, W, U, lr, bias, out);
}